// Round 1
// baseline (1048.340 us; speedup 1.0000x reference)
//
#include <hip/hip_runtime.h>

// Problem: out[m][n] = sum_k X[m][k] * Wq[n][k] * scale[n] + bias[n]
// M = 8192 (B*S), N = 4096 (D_OUT), K = 4096 (D_IN)
// X fp32 row-major [M][K]; Wq int32 row-major [N][K] (ternary {-1,0,1});
// scale fp32 [N]; bias fp32 [N]; Out fp32 [M][N].
//
// Strategy: bf16 MFMA GEMM (C = A * B^T, both operands K-major), with
// fp32->bf16 / int32->bf16 conversion fused into the LDS staging step.
// scale applied in fp32 epilogue so ternary weights are exact in bf16.

#define MDIM 8192
#define NDIM 4096
#define KDIM 4096
#define BM 128
#define BN 128
#define BK 64
#define LDSS 72  // ushorts per LDS row: 64 + 8 pad (144 B, 16B-aligned rows)

typedef __bf16 bf16x8 __attribute__((ext_vector_type(8)));
typedef float f32x4 __attribute__((ext_vector_type(4)));

// round-to-nearest-even fp32 -> bf16, two at a time, packed into one u32
__device__ __forceinline__ unsigned f2bf_pack(float lo, float hi) {
    unsigned a = __float_as_uint(lo);
    unsigned b = __float_as_uint(hi);
    a += 0x7FFFu + ((a >> 16) & 1u);
    b += 0x7FFFu + ((b >> 16) & 1u);
    return (a >> 16) | (b & 0xFFFF0000u);
}

// ternary int -> bf16 (exact: -1,0,1 representable), packed pair
__device__ __forceinline__ unsigned w2bf_pack(int lo, int hi) {
    unsigned a = __float_as_uint((float)lo) >> 16;
    unsigned b = __float_as_uint((float)hi) & 0xFFFF0000u;
    return a | b;
}

__global__ __launch_bounds__(256, 2)
void ternary_gemm(const float* __restrict__ X, const int* __restrict__ Wq,
                  const float* __restrict__ scale, const float* __restrict__ bias,
                  float* __restrict__ Out) {
    __shared__ unsigned short As[BM * LDSS];
    __shared__ unsigned short Bs[BN * LDSS];

    const int tid  = threadIdx.x;
    const int lane = tid & 63;
    const int wave = tid >> 6;
    const int quad = lane >> 4;
    const int l16  = lane & 15;
    const int wm   = (wave >> 1) * 64;  // wave's m-offset within tile
    const int wn   = (wave & 1) * 64;   // wave's n-offset within tile

    const int m0 = blockIdx.y * BM;
    const int n0 = blockIdx.x * BN;

    // staging: 16 threads per row, 4 floats per thread, 16 rows per step, 8 steps
    const int srow = tid >> 4;         // 0..15
    const int scol = (tid & 15) * 4;   // 0,4,...,60 (float index within BK)

    const float* Aptr = X  + (size_t)(m0 + srow) * KDIM + scol;
    const int*   Bptr = Wq + (size_t)(n0 + srow) * KDIM + scol;

    f32x4 acc[4][4];
#pragma unroll
    for (int i = 0; i < 4; i++)
#pragma unroll
        for (int j = 0; j < 4; j++)
            acc[i][j] = (f32x4){0.f, 0.f, 0.f, 0.f};

    for (int kt = 0; kt < KDIM; kt += BK) {
        uint2 apk[8], bpk[8];
#pragma unroll
        for (int j = 0; j < 8; j++) {
            const f32x4 av = *(const f32x4*)(Aptr + (size_t)j * 16 * KDIM + kt);
            apk[j].x = f2bf_pack(av.x, av.y);
            apk[j].y = f2bf_pack(av.z, av.w);
        }
#pragma unroll
        for (int j = 0; j < 8; j++) {
            const int4 bv = *(const int4*)(Bptr + (size_t)j * 16 * KDIM + kt);
            bpk[j].x = w2bf_pack(bv.x, bv.y);
            bpk[j].y = w2bf_pack(bv.z, bv.w);
        }
        __syncthreads();  // previous iter's LDS reads done
#pragma unroll
        for (int j = 0; j < 8; j++) {
            *(uint2*)&As[(srow + j * 16) * LDSS + scol] = apk[j];
            *(uint2*)&Bs[(srow + j * 16) * LDSS + scol] = bpk[j];
        }
        __syncthreads();  // LDS tile visible

#pragma unroll
        for (int h = 0; h < 2; h++) {  // two K=32 halves of BK=64
            bf16x8 af[4], bf[4];
#pragma unroll
            for (int mt = 0; mt < 4; mt++)
                af[mt] = *(const bf16x8*)&As[(wm + mt * 16 + l16) * LDSS + h * 32 + quad * 8];
#pragma unroll
            for (int nt = 0; nt < 4; nt++)
                bf[nt] = *(const bf16x8*)&Bs[(wn + nt * 16 + l16) * LDSS + h * 32 + quad * 8];
#pragma unroll
            for (int mt = 0; mt < 4; mt++)
#pragma unroll
                for (int nt = 0; nt < 4; nt++)
                    acc[mt][nt] = __builtin_amdgcn_mfma_f32_16x16x32_bf16(
                        af[mt], bf[nt], acc[mt][nt], 0, 0, 0);
        }
    }

    // epilogue: C/D layout col = lane&15, row = quad*4 + r
#pragma unroll
    for (int nt = 0; nt < 4; nt++) {
        const int n = n0 + wn + nt * 16 + l16;
        const float sc = scale[n];
        const float bi = bias[n];
#pragma unroll
        for (int mt = 0; mt < 4; mt++) {
#pragma unroll
            for (int r = 0; r < 4; r++) {
                const int m = m0 + wm + mt * 16 + quad * 4 + r;
                Out[(size_t)m * NDIM + n] = acc[mt][nt][r] * sc + bi;
            }
        }
    }
}

extern "C" void kernel_launch(void* const* d_in, const int* in_sizes, int n_in,
                              void* d_out, int out_size, void* d_ws, size_t ws_size,
                              hipStream_t stream) {
    const float* x     = (const float*)d_in[0];
    const int*   wq    = (const int*)d_in[1];
    const float* scale = (const float*)d_in[2];
    const float* bias  = (const float*)d_in[3];
    float* out = (float*)d_out;

    dim3 grid(NDIM / BN, MDIM / BM);  // (32, 64): blocks sharing an A-panel adjacent
    ternary_gemm<<<grid, dim3(256), 0, stream>>>(x, wq, scale, bias, out);
}

// Round 2
// 716.770 us; speedup vs baseline: 1.4626x; 1.4626x over previous
//
#include <hip/hip_runtime.h>

// out[m][n] = sum_k X[m][k] * Wq[n][k] * scale[n] + bias[n]
// M=8192, N=4096, K=4096. X fp32 [M][K]; Wq int32 ternary [N][K];
// scale fp32 [N]; bias fp32 [N]; Out fp32 [M][N].
//
// Round 2: pre-convert X and Wq to bf16 in d_ws (two memory-bound passes),
// then m97-style MFMA GEMM with global_load_lds width=16 into unpadded LDS,
// XOR-swizzled (chunk ^ row&7) to avoid bank conflicts without padding.
// Fallback to round-1 fused kernel if ws_size is too small.

#define MDIM 8192
#define NDIM 4096
#define KDIM 4096
#define BM 128
#define BN 128
#define BK 64

typedef __bf16 bf16x8 __attribute__((ext_vector_type(8)));
typedef float f32x4 __attribute__((ext_vector_type(4)));

// round-to-nearest-even fp32 -> bf16, two at a time, packed into one u32
__device__ __forceinline__ unsigned f2bf_pack(float lo, float hi) {
    unsigned a = __float_as_uint(lo);
    unsigned b = __float_as_uint(hi);
    a += 0x7FFFu + ((a >> 16) & 1u);
    b += 0x7FFFu + ((b >> 16) & 1u);
    return (a >> 16) | (b & 0xFFFF0000u);
}

// ternary int -> bf16 (exact), packed pair
__device__ __forceinline__ unsigned w2bf_pack(int lo, int hi) {
    unsigned a = __float_as_uint((float)lo) >> 16;
    unsigned b = __float_as_uint((float)hi) & 0xFFFF0000u;
    return a | b;
}

__device__ __forceinline__ void async_load16(const void* gptr, void* lptr) {
    __builtin_amdgcn_global_load_lds(
        (const __attribute__((address_space(1))) void*)gptr,
        (__attribute__((address_space(3))) void*)lptr, 16, 0, 0);
}

// ---------------- conversion passes ----------------

__global__ void convert_x(const float* __restrict__ in, unsigned* __restrict__ out) {
    // 8192*4096 floats, 4 per thread
    const size_t i = (size_t)blockIdx.x * blockDim.x + threadIdx.x;
    const f32x4 v = ((const f32x4*)in)[i];
    ((uint2*)out)[i] = make_uint2(f2bf_pack(v.x, v.y), f2bf_pack(v.z, v.w));
}

__global__ void convert_w(const int* __restrict__ in, unsigned* __restrict__ out) {
    // 4096*4096 ints, 4 per thread
    const size_t i = (size_t)blockIdx.x * blockDim.x + threadIdx.x;
    const int4 v = ((const int4*)in)[i];
    ((uint2*)out)[i] = make_uint2(w2bf_pack(v.x, v.y), w2bf_pack(v.z, v.w));
}

// ---------------- main GEMM (bf16 in, fp32 out) ----------------
// A = Xb [M][K] bf16 row-major, B = Wb [N][K] bf16 row-major, C = A*B^T.
// LDS tile: [128 rows][64 bf16] = 128 B/row, 8 chunks of 16 B per row.
// Data chunk c of row r is stored at LDS chunk (c ^ (r&7)).

__global__ void gemm_bf16(const unsigned short* __restrict__ Xb,
                          const unsigned short* __restrict__ Wb,
                          const float* __restrict__ scale,
                          const float* __restrict__ bias,
                          float* __restrict__ Out) {
    __shared__ unsigned short As[BM * BK];  // 16 KB
    __shared__ unsigned short Bs[BN * BK];  // 16 KB

    const int tid  = threadIdx.x;
    const int lane = tid & 63;
    const int wave = tid >> 6;
    const int quad = lane >> 4;
    const int l16  = lane & 15;
    const int wm   = (wave >> 1) * 64;
    const int wn   = (wave & 1) * 64;

    const int m0 = blockIdx.y * BM;
    const int n0 = blockIdx.x * BN;

    // staging mapping: wave w, instruction j covers rows [w*32+j*8, +8).
    // lane -> row_local = lane/8, lds chunk = lane%8, data chunk = (lane%8)^(lane/8)
    const int lr = lane >> 3;                 // 0..7
    const int lc = lane & 7;                  // 0..7
    const int cc = lc ^ lr;                   // swizzled data chunk

    const unsigned short* pA[4];
    const unsigned short* pB[4];
    char* ldsA[4];
    char* ldsB[4];
#pragma unroll
    for (int j = 0; j < 4; j++) {
        const int rlocal = wave * 32 + j * 8 + lr;
        pA[j] = Xb + (size_t)(m0 + rlocal) * KDIM + cc * 8;
        pB[j] = Wb + (size_t)(n0 + rlocal) * KDIM + cc * 8;
        ldsA[j] = (char*)As + (wave * 32 + j * 8) * 128;  // wave-uniform base
        ldsB[j] = (char*)Bs + (wave * 32 + j * 8) * 128;
    }

    f32x4 acc[4][4];
#pragma unroll
    for (int i = 0; i < 4; i++)
#pragma unroll
        for (int j = 0; j < 4; j++)
            acc[i][j] = (f32x4){0.f, 0.f, 0.f, 0.f};

    for (int kt = 0; kt < KDIM; kt += BK) {
#pragma unroll
        for (int j = 0; j < 4; j++) async_load16(pA[j] + kt, ldsA[j]);
#pragma unroll
        for (int j = 0; j < 4; j++) async_load16(pB[j] + kt, ldsB[j]);

        __syncthreads();  // compiler emits vmcnt(0) drain before barrier

        const int sw = l16 & 7;  // row&7 for fragment rows
#pragma unroll
        for (int h = 0; h < 2; h++) {
            bf16x8 af[4], bf[4];
#pragma unroll
            for (int mt = 0; mt < 4; mt++) {
                const int row = wm + mt * 16 + l16;
                af[mt] = *(const bf16x8*)((const char*)As + row * 128 +
                                          ((h * 4 + quad) ^ sw) * 16);
            }
#pragma unroll
            for (int nt = 0; nt < 4; nt++) {
                const int row = wn + nt * 16 + l16;
                bf[nt] = *(const bf16x8*)((const char*)Bs + row * 128 +
                                          ((h * 4 + quad) ^ sw) * 16);
            }
#pragma unroll
            for (int mt = 0; mt < 4; mt++)
#pragma unroll
                for (int nt = 0; nt < 4; nt++)
                    acc[mt][nt] = __builtin_amdgcn_mfma_f32_16x16x32_bf16(
                        af[mt], bf[nt], acc[mt][nt], 0, 0, 0);
        }
        __syncthreads();  // protect LDS from next iter's loads
    }

    // epilogue: C/D layout col = lane&15, row = quad*4 + r (verified round 1)
#pragma unroll
    for (int nt = 0; nt < 4; nt++) {
        const int n = n0 + wn + nt * 16 + l16;
        const float sc = scale[n];
        const float bi = bias[n];
#pragma unroll
        for (int mt = 0; mt < 4; mt++) {
#pragma unroll
            for (int r = 0; r < 4; r++) {
                const int m = m0 + wm + mt * 16 + quad * 4 + r;
                Out[(size_t)m * NDIM + n] = acc[mt][nt][r] * sc + bi;
            }
        }
    }
}

// ---------------- round-1 fused fallback (if ws too small) ----------------

#define LDSS 72

__global__ __launch_bounds__(256, 2)
void ternary_gemm_fused(const float* __restrict__ X, const int* __restrict__ Wq,
                        const float* __restrict__ scale, const float* __restrict__ bias,
                        float* __restrict__ Out) {
    __shared__ unsigned short As[BM * LDSS];
    __shared__ unsigned short Bs[BN * LDSS];

    const int tid  = threadIdx.x;
    const int lane = tid & 63;
    const int wave = tid >> 6;
    const int quad = lane >> 4;
    const int l16  = lane & 15;
    const int wm   = (wave >> 1) * 64;
    const int wn   = (wave & 1) * 64;

    const int m0 = blockIdx.y * BM;
    const int n0 = blockIdx.x * BN;

    const int srow = tid >> 4;
    const int scol = (tid & 15) * 4;

    const float* Aptr = X  + (size_t)(m0 + srow) * KDIM + scol;
    const int*   Bptr = Wq + (size_t)(n0 + srow) * KDIM + scol;

    f32x4 acc[4][4];
#pragma unroll
    for (int i = 0; i < 4; i++)
#pragma unroll
        for (int j = 0; j < 4; j++)
            acc[i][j] = (f32x4){0.f, 0.f, 0.f, 0.f};

    for (int kt = 0; kt < KDIM; kt += BK) {
        uint2 apk[8], bpk[8];
#pragma unroll
        for (int j = 0; j < 8; j++) {
            const f32x4 av = *(const f32x4*)(Aptr + (size_t)j * 16 * KDIM + kt);
            apk[j].x = f2bf_pack(av.x, av.y);
            apk[j].y = f2bf_pack(av.z, av.w);
        }
#pragma unroll
        for (int j = 0; j < 8; j++) {
            const int4 bv = *(const int4*)(Bptr + (size_t)j * 16 * KDIM + kt);
            bpk[j].x = w2bf_pack(bv.x, bv.y);
            bpk[j].y = w2bf_pack(bv.z, bv.w);
        }
        __syncthreads();
#pragma unroll
        for (int j = 0; j < 8; j++) {
            *(uint2*)&As[(srow + j * 16) * LDSS + scol] = apk[j];
            *(uint2*)&Bs[(srow + j * 16) * LDSS + scol] = bpk[j];
        }
        __syncthreads();

#pragma unroll
        for (int h = 0; h < 2; h++) {
            bf16x8 af[4], bf[4];
#pragma unroll
            for (int mt = 0; mt < 4; mt++)
                af[mt] = *(const bf16x8*)&As[(wm + mt * 16 + l16) * LDSS + h * 32 + quad * 8];
#pragma unroll
            for (int nt = 0; nt < 4; nt++)
                bf[nt] = *(const bf16x8*)&Bs[(wn + nt * 16 + l16) * LDSS + h * 32 + quad * 8];
#pragma unroll
            for (int mt = 0; mt < 4; mt++)
#pragma unroll
                for (int nt = 0; nt < 4; nt++)
                    acc[mt][nt] = __builtin_amdgcn_mfma_f32_16x16x32_bf16(
                        af[mt], bf[nt], acc[mt][nt], 0, 0, 0);
        }
    }

#pragma unroll
    for (int nt = 0; nt < 4; nt++) {
        const int n = n0 + wn + nt * 16 + l16;
        const float sc = scale[n];
        const float bi = bias[n];
#pragma unroll
        for (int mt = 0; mt < 4; mt++) {
#pragma unroll
            for (int r = 0; r < 4; r++) {
                const int m = m0 + wm + mt * 16 + quad * 4 + r;
                Out[(size_t)m * NDIM + n] = acc[mt][nt][r] * sc + bi;
            }
        }
    }
}

extern "C" void kernel_launch(void* const* d_in, const int* in_sizes, int n_in,
                              void* d_out, int out_size, void* d_ws, size_t ws_size,
                              hipStream_t stream) {
    const float* x     = (const float*)d_in[0];
    const int*   wq    = (const int*)d_in[1];
    const float* scale = (const float*)d_in[2];
    const float* bias  = (const float*)d_in[3];
    float* out = (float*)d_out;

    const size_t xb_bytes = (size_t)MDIM * KDIM * 2;  // 67,108,864
    const size_t wb_bytes = (size_t)NDIM * KDIM * 2;  // 33,554,432

    if (ws_size >= xb_bytes + wb_bytes) {
        unsigned short* Xb = (unsigned short*)d_ws;
        unsigned short* Wb = (unsigned short*)((char*)d_ws + xb_bytes);

        convert_x<<<(MDIM * (size_t)KDIM) / 4 / 256, 256, 0, stream>>>(x, (unsigned*)Xb);
        convert_w<<<(NDIM * (size_t)KDIM) / 4 / 256, 256, 0, stream>>>(wq, (unsigned*)Wb);

        dim3 grid(NDIM / BN, MDIM / BM);  // (32, 64)
        gemm_bf16<<<grid, dim3(256), 0, stream>>>(Xb, Wb, scale, bias, out);
    } else {
        dim3 grid(NDIM / BN, MDIM / BM);
        ternary_gemm_fused<<<grid, dim3(256), 0, stream>>>(x, wq, scale, bias, out);
    }
}

// Round 3
// 576.938 us; speedup vs baseline: 1.8171x; 1.2424x over previous
//
#include <hip/hip_runtime.h>

// out[m][n] = sum_k X[m][k] * Wq[n][k] * scale[n] + bias[n]
// M=8192, N=4096, K=4096. X fp32 [M][K]; Wq int32 ternary [N][K];
// scale fp32 [N]; bias fp32 [N]; Out fp32 [M][N].
//
// Round 3: (a) double-buffered LDS, prefetch for tile k+1 issued BEFORE
// compute on tile k, so the barrier's vmcnt(0) drain finds the loads
// already landed; (b) converts fused into one dispatch, 16B loads+stores.
// Fallback to round-1 fused kernel if ws_size is too small.

#define MDIM 8192
#define NDIM 4096
#define KDIM 4096
#define BM 128
#define BN 128
#define BK 64

typedef __bf16 bf16x8 __attribute__((ext_vector_type(8)));
typedef float f32x4 __attribute__((ext_vector_type(4)));

__device__ __forceinline__ unsigned f2bf_pack(float lo, float hi) {
    unsigned a = __float_as_uint(lo);
    unsigned b = __float_as_uint(hi);
    a += 0x7FFFu + ((a >> 16) & 1u);
    b += 0x7FFFu + ((b >> 16) & 1u);
    return (a >> 16) | (b & 0xFFFF0000u);
}

__device__ __forceinline__ unsigned w2bf_pack(int lo, int hi) {
    unsigned a = __float_as_uint((float)lo) >> 16;
    unsigned b = __float_as_uint((float)hi) & 0xFFFF0000u;
    return a | b;
}

__device__ __forceinline__ void async_load16(const void* gptr, void* lptr) {
    __builtin_amdgcn_global_load_lds(
        (const __attribute__((address_space(1))) void*)gptr,
        (__attribute__((address_space(3))) void*)lptr, 16, 0, 0);
}

// ---------------- fused conversion pass ----------------
// X: 8192*4096 fp32 -> bf16; W: 4096*4096 i32 -> bf16. 8 elements/thread.
#define XGROUPS ((MDIM * (size_t)KDIM) / 8)   // 4M threads for X
#define WGROUPS ((NDIM * (size_t)KDIM) / 8)   // 2M threads for W

__global__ void convert_all(const float* __restrict__ X, const int* __restrict__ Wq,
                            uint4* __restrict__ Xb, uint4* __restrict__ Wb) {
    const size_t gid = (size_t)blockIdx.x * blockDim.x + threadIdx.x;
    if (gid < XGROUPS) {
        const f32x4 a = ((const f32x4*)X)[2 * gid];
        const f32x4 b = ((const f32x4*)X)[2 * gid + 1];
        Xb[gid] = make_uint4(f2bf_pack(a.x, a.y), f2bf_pack(a.z, a.w),
                             f2bf_pack(b.x, b.y), f2bf_pack(b.z, b.w));
    } else {
        const size_t wi = gid - XGROUPS;
        const int4 a = ((const int4*)Wq)[2 * wi];
        const int4 b = ((const int4*)Wq)[2 * wi + 1];
        Wb[wi] = make_uint4(w2bf_pack(a.x, a.y), w2bf_pack(a.z, a.w),
                            w2bf_pack(b.x, b.y), w2bf_pack(b.z, b.w));
    }
}

// ---------------- main GEMM (bf16 in, fp32 out) ----------------
// LDS tile: [128 rows][64 bf16] = 128 B/row, 8 chunks of 16 B per row.
// Data chunk c of row r stored at LDS chunk (c ^ (r&7)).  Double-buffered.

__global__ __launch_bounds__(256)
void gemm_bf16(const unsigned short* __restrict__ Xb,
               const unsigned short* __restrict__ Wb,
               const float* __restrict__ scale,
               const float* __restrict__ bias,
               float* __restrict__ Out) {
    __shared__ unsigned short As[2][BM * BK];  // 2 x 16 KB
    __shared__ unsigned short Bs[2][BN * BK];  // 2 x 16 KB

    const int tid  = threadIdx.x;
    const int lane = tid & 63;
    const int wave = tid >> 6;
    const int quad = lane >> 4;
    const int l16  = lane & 15;
    const int wm   = (wave >> 1) * 64;
    const int wn   = (wave & 1) * 64;

    const int m0 = blockIdx.y * BM;
    const int n0 = blockIdx.x * BN;

    // staging: wave w, instr j covers rows [w*32 + j*8, +8)
    const int lr = lane >> 3;   // 0..7 row within 8-row group
    const int lc = lane & 7;    // 0..7 lds chunk
    const int cc = lc ^ lr;     // swizzled data chunk

    const unsigned short* pA[4];
    const unsigned short* pB[4];
    char* ldsA[2][4];
    char* ldsB[2][4];
#pragma unroll
    for (int j = 0; j < 4; j++) {
        const int rlocal = wave * 32 + j * 8 + lr;
        pA[j] = Xb + (size_t)(m0 + rlocal) * KDIM + cc * 8;
        pB[j] = Wb + (size_t)(n0 + rlocal) * KDIM + cc * 8;
#pragma unroll
        for (int b = 0; b < 2; b++) {
            ldsA[b][j] = (char*)As[b] + (wave * 32 + j * 8) * 128;  // wave-uniform base
            ldsB[b][j] = (char*)Bs[b] + (wave * 32 + j * 8) * 128;
        }
    }

    f32x4 acc[4][4];
#pragma unroll
    for (int i = 0; i < 4; i++)
#pragma unroll
        for (int j = 0; j < 4; j++)
            acc[i][j] = (f32x4){0.f, 0.f, 0.f, 0.f};

    const int sw = l16 & 7;

    // prefetch helper (macro-free lambdas keep addressing in registers)
    auto prefetch = [&](int kt, int buf) {
#pragma unroll
        for (int j = 0; j < 4; j++) async_load16(pA[j] + kt, ldsA[buf][j]);
#pragma unroll
        for (int j = 0; j < 4; j++) async_load16(pB[j] + kt, ldsB[buf][j]);
    };

    auto compute = [&](int buf) {
#pragma unroll
        for (int h = 0; h < 2; h++) {
            bf16x8 af[4], bf[4];
#pragma unroll
            for (int mt = 0; mt < 4; mt++) {
                const int row = wm + mt * 16 + l16;
                af[mt] = *(const bf16x8*)((const char*)As[buf] + row * 128 +
                                          ((h * 4 + quad) ^ sw) * 16);
            }
#pragma unroll
            for (int nt = 0; nt < 4; nt++) {
                const int row = wn + nt * 16 + l16;
                bf[nt] = *(const bf16x8*)((const char*)Bs[buf] + row * 128 +
                                          ((h * 4 + quad) ^ sw) * 16);
            }
#pragma unroll
            for (int mt = 0; mt < 4; mt++)
#pragma unroll
                for (int nt = 0; nt < 4; nt++)
                    acc[mt][nt] = __builtin_amdgcn_mfma_f32_16x16x32_bf16(
                        af[mt], bf[nt], acc[mt][nt], 0, 0, 0);
        }
    };

    prefetch(0, 0);
    __syncthreads();  // buf0 ready

    for (int kt = 0; kt < KDIM; kt += 2 * BK) {
        prefetch(kt + BK, 1);        // kt+64 <= 4032, always valid
        compute(0);
        __syncthreads();             // drains buf1 loads (landed during compute)
        if (kt + 2 * BK < KDIM) prefetch(kt + 2 * BK, 0);
        compute(1);
        __syncthreads();
    }

    // epilogue: C/D layout col = lane&15, row = quad*4 + r (verified)
#pragma unroll
    for (int nt = 0; nt < 4; nt++) {
        const int n = n0 + wn + nt * 16 + l16;
        const float sc = scale[n];
        const float bi = bias[n];
#pragma unroll
        for (int mt = 0; mt < 4; mt++) {
#pragma unroll
            for (int r = 0; r < 4; r++) {
                const int m = m0 + wm + mt * 16 + quad * 4 + r;
                Out[(size_t)m * NDIM + n] = acc[mt][nt][r] * sc + bi;
            }
        }
    }
}

// ---------------- round-1 fused fallback (if ws too small) ----------------

#define LDSS 72

__global__ __launch_bounds__(256, 2)
void ternary_gemm_fused(const float* __restrict__ X, const int* __restrict__ Wq,
                        const float* __restrict__ scale, const float* __restrict__ bias,
                        float* __restrict__ Out) {
    __shared__ unsigned short As[BM * LDSS];
    __shared__ unsigned short Bs[BN * LDSS];

    const int tid  = threadIdx.x;
    const int lane = tid & 63;
    const int wave = tid >> 6;
    const int quad = lane >> 4;
    const int l16  = lane & 15;
    const int wm   = (wave >> 1) * 64;
    const int wn   = (wave & 1) * 64;

    const int m0 = blockIdx.y * BM;
    const int n0 = blockIdx.x * BN;

    const int srow = tid >> 4;
    const int scol = (tid & 15) * 4;

    const float* Aptr = X  + (size_t)(m0 + srow) * KDIM + scol;
    const int*   Bptr = Wq + (size_t)(n0 + srow) * KDIM + scol;

    f32x4 acc[4][4];
#pragma unroll
    for (int i = 0; i < 4; i++)
#pragma unroll
        for (int j = 0; j < 4; j++)
            acc[i][j] = (f32x4){0.f, 0.f, 0.f, 0.f};

    for (int kt = 0; kt < KDIM; kt += BK) {
        uint2 apk[8], bpk[8];
#pragma unroll
        for (int j = 0; j < 8; j++) {
            const f32x4 av = *(const f32x4*)(Aptr + (size_t)j * 16 * KDIM + kt);
            apk[j].x = f2bf_pack(av.x, av.y);
            apk[j].y = f2bf_pack(av.z, av.w);
        }
#pragma unroll
        for (int j = 0; j < 8; j++) {
            const int4 bv = *(const int4*)(Bptr + (size_t)j * 16 * KDIM + kt);
            bpk[j].x = w2bf_pack(bv.x, bv.y);
            bpk[j].y = w2bf_pack(bv.z, bv.w);
        }
        __syncthreads();
#pragma unroll
        for (int j = 0; j < 8; j++) {
            *(uint2*)&As[(srow + j * 16) * LDSS + scol] = apk[j];
            *(uint2*)&Bs[(srow + j * 16) * LDSS + scol] = bpk[j];
        }
        __syncthreads();

#pragma unroll
        for (int h = 0; h < 2; h++) {
            bf16x8 af[4], bf[4];
#pragma unroll
            for (int mt = 0; mt < 4; mt++)
                af[mt] = *(const bf16x8*)&As[(wm + mt * 16 + l16) * LDSS + h * 32 + quad * 8];
#pragma unroll
            for (int nt = 0; nt < 4; nt++)
                bf[nt] = *(const bf16x8*)&Bs[(wn + nt * 16 + l16) * LDSS + h * 32 + quad * 8];
#pragma unroll
            for (int mt = 0; mt < 4; mt++)
#pragma unroll
                for (int nt = 0; nt < 4; nt++)
                    acc[mt][nt] = __builtin_amdgcn_mfma_f32_16x16x32_bf16(
                        af[mt], bf[nt], acc[mt][nt], 0, 0, 0);
        }
    }

#pragma unroll
    for (int nt = 0; nt < 4; nt++) {
        const int n = n0 + wn + nt * 16 + l16;
        const float sc = scale[n];
        const float bi = bias[n];
#pragma unroll
        for (int mt = 0; mt < 4; mt++) {
#pragma unroll
            for (int r = 0; r < 4; r++) {
                const int m = m0 + wm + mt * 16 + quad * 4 + r;
                Out[(size_t)m * NDIM + n] = acc[mt][nt][r] * sc + bi;
            }
        }
    }
}

extern "C" void kernel_launch(void* const* d_in, const int* in_sizes, int n_in,
                              void* d_out, int out_size, void* d_ws, size_t ws_size,
                              hipStream_t stream) {
    const float* x     = (const float*)d_in[0];
    const int*   wq    = (const int*)d_in[1];
    const float* scale = (const float*)d_in[2];
    const float* bias  = (const float*)d_in[3];
    float* out = (float*)d_out;

    const size_t xb_bytes = (size_t)MDIM * KDIM * 2;  // 64 MiB
    const size_t wb_bytes = (size_t)NDIM * KDIM * 2;  // 32 MiB

    if (ws_size >= xb_bytes + wb_bytes) {
        unsigned short* Xb = (unsigned short*)d_ws;
        unsigned short* Wb = (unsigned short*)((char*)d_ws + xb_bytes);

        const size_t total_groups = XGROUPS + WGROUPS;  // 6M threads
        convert_all<<<(unsigned)(total_groups / 256), 256, 0, stream>>>(
            x, wq, (uint4*)Xb, (uint4*)Wb);

        dim3 grid(NDIM / BN, MDIM / BM);  // (32, 64)
        gemm_bf16<<<grid, dim3(256), 0, stream>>>(Xb, Wb, scale, bias, out);
    } else {
        dim3 grid(NDIM / BN, MDIM / BM);
        ternary_gemm_fused<<<grid, dim3(256), 0, stream>>>(x, wq, scale, bias, out);
    }
}